// Round 1
// baseline (110.583 us; speedup 1.0000x reference)
//
#include <hip/hip_runtime.h>

#define NC 256
#define NB 32
#define HW 4096
#define HW4 1024
#define KC 768   // KERNEL * NC
#define BN_EPS 1e-5f

// ---------------- Kernel 1: global average pool per (b,c) ----------------
// one block per (b,c) plane; 256 threads; 4 float4 loads each (16KB plane)
__global__ __launch_bounds__(256) void gap_kernel(const float* __restrict__ x,
                                                  float* __restrict__ g) {
    const int bc = blockIdx.x;
    const float4* xp = reinterpret_cast<const float4*>(x) + (size_t)bc * HW4;
    const int t = threadIdx.x;
    float s = 0.f;
#pragma unroll
    for (int k = 0; k < 4; ++k) {
        float4 v = xp[t + k * 256];
        s += (v.x + v.y) + (v.z + v.w);
    }
    // wave (64-lane) tree reduce
#pragma unroll
    for (int off = 32; off > 0; off >>= 1) s += __shfl_down(s, off, 64);
    __shared__ float warp_sums[4];
    const int lane = t & 63, w = t >> 6;
    if (lane == 0) warp_sums[w] = s;
    __syncthreads();
    if (t == 0) {
        float tot = (warp_sums[0] + warp_sums[1]) + (warp_sums[2] + warp_sums[3]);
        g[bc] = tot * (1.0f / HW);
    }
}

// ---------------- Kernel 2: 1x1 conv (768x256 dot) + BN + tanh ----------------
// one block per batch element; g[b,:] staged in LDS; thread t computes
// outputs j = t, t+256, t+512 (i.e. k=0,1,2 taps for channel c=t)
__global__ __launch_bounds__(256) void filt_kernel(const float* __restrict__ g,
                                                   const float* __restrict__ cw,
                                                   const float* __restrict__ bn_w,
                                                   const float* __restrict__ bn_b,
                                                   const float* __restrict__ bn_m,
                                                   const float* __restrict__ bn_v,
                                                   float* __restrict__ f) {
    const int b = blockIdx.x;
    const int t = threadIdx.x;
    __shared__ float gs[NC];
    gs[t] = g[b * NC + t];
    __syncthreads();
#pragma unroll
    for (int r = 0; r < 3; ++r) {
        const int j = r * NC + t;
        const float* wr = cw + (size_t)j * NC;
        float a0 = 0.f, a1 = 0.f, a2 = 0.f, a3 = 0.f;
#pragma unroll 4
        for (int c = 0; c < NC; c += 4) {
            a0 = fmaf(gs[c + 0], wr[c + 0], a0);
            a1 = fmaf(gs[c + 1], wr[c + 1], a1);
            a2 = fmaf(gs[c + 2], wr[c + 2], a2);
            a3 = fmaf(gs[c + 3], wr[c + 3], a3);
        }
        float acc = (a0 + a1) + (a2 + a3);
        float yn = (acc - bn_m[j]) * rsqrtf(bn_v[j] + BN_EPS) * bn_w[j] + bn_b[j];
        f[b * KC + j] = tanhf(yn);
    }
}

// ---------------- Kernel 3: dynamic channel-local filter + affine ----------------
// out[b,c,hw] = (f0*x[b,refl(c-1),hw] + f1*x[b,c,hw] + f2*x[b,refl(c+1),hw])*gamma[c]
//               + x[b,c,hw]*beta[c]
__global__ __launch_bounds__(256) void apply_kernel(const float* __restrict__ x,
                                                    const float* __restrict__ f,
                                                    const float* __restrict__ gamma,
                                                    const float* __restrict__ beta,
                                                    float* __restrict__ out) {
    const float4* x4 = reinterpret_cast<const float4*>(x);
    float4* o4 = reinterpret_cast<float4*>(out);
    const int total = NB * NC * HW4;  // 8,388,608
    for (int i = blockIdx.x * blockDim.x + threadIdx.x; i < total;
         i += gridDim.x * blockDim.x) {
        const int hw = i & (HW4 - 1);
        const int c  = (i >> 10) & (NC - 1);
        const int b  = i >> 18;
        const int cm = (c == 0) ? 1 : c - 1;
        const int cp = (c == NC - 1) ? NC - 2 : c + 1;
        const size_t base = (size_t)b * NC * HW4;
        float4 xm = x4[base + (size_t)cm * HW4 + hw];
        float4 xc = x4[base + (size_t)c  * HW4 + hw];
        float4 xq = x4[base + (size_t)cp * HW4 + hw];
        // f loads are wave-uniform (c constant across a wave's 64 lanes)
        const float f0 = f[b * KC + c];
        const float f1 = f[b * KC + NC + c];
        const float f2 = f[b * KC + 2 * NC + c];
        const float ga = gamma[c];
        const float be = beta[c];
        float4 r;
        r.x = fmaf(fmaf(f0, xm.x, fmaf(f1, xc.x, f2 * xq.x)), ga, xc.x * be);
        r.y = fmaf(fmaf(f0, xm.y, fmaf(f1, xc.y, f2 * xq.y)), ga, xc.y * be);
        r.z = fmaf(fmaf(f0, xm.z, fmaf(f1, xc.z, f2 * xq.z)), ga, xc.z * be);
        r.w = fmaf(fmaf(f0, xm.w, fmaf(f1, xc.w, f2 * xq.w)), ga, xc.w * be);
        o4[i] = r;
    }
}

extern "C" void kernel_launch(void* const* d_in, const int* in_sizes, int n_in,
                              void* d_out, int out_size, void* d_ws, size_t ws_size,
                              hipStream_t stream) {
    const float* x     = (const float*)d_in[0];
    const float* cw    = (const float*)d_in[1];
    const float* bn_w  = (const float*)d_in[2];
    const float* bn_b  = (const float*)d_in[3];
    const float* bn_m  = (const float*)d_in[4];
    const float* bn_v  = (const float*)d_in[5];
    const float* gamma = (const float*)d_in[6];
    const float* beta  = (const float*)d_in[7];
    float* out = (float*)d_out;

    float* g = (float*)d_ws;                    // NB*NC floats   (32 KB)
    float* f = g + NB * NC;                     // NB*KC floats   (96 KB)

    gap_kernel<<<NB * NC, 256, 0, stream>>>(x, g);
    filt_kernel<<<NB, 256, 0, stream>>>(g, cw, bn_w, bn_b, bn_m, bn_v, f);
    apply_kernel<<<2048, 256, 0, stream>>>(x, f, gamma, beta, out);
}

// Round 3
// 86.694 us; speedup vs baseline: 1.2755x; 1.2755x over previous
//
#include <hip/hip_runtime.h>

#define NC 256
#define NB 32
#define HW 4096
#define HW4 1024
#define KC 768   // KERNEL * NC
#define BN_EPS 1e-5f

typedef float f32x4 __attribute__((ext_vector_type(4)));

// ---------------- Kernel 1: global average pool per (b,c) ----------------
// one block per (b,c) plane; 256 threads; 4 float4 loads each (16KB plane)
__global__ __launch_bounds__(256) void gap_kernel(const float* __restrict__ x,
                                                  float* __restrict__ g) {
    const int bc = blockIdx.x;
    const f32x4* xp = reinterpret_cast<const f32x4*>(x) + (size_t)bc * HW4;
    const int t = threadIdx.x;
    float s = 0.f;
#pragma unroll
    for (int k = 0; k < 4; ++k) {
        f32x4 v = xp[t + k * 256];
        s += (v.x + v.y) + (v.z + v.w);
    }
#pragma unroll
    for (int off = 32; off > 0; off >>= 1) s += __shfl_down(s, off, 64);
    __shared__ float warp_sums[4];
    const int lane = t & 63, w = t >> 6;
    if (lane == 0) warp_sums[w] = s;
    __syncthreads();
    if (t == 0) {
        float tot = (warp_sums[0] + warp_sums[1]) + (warp_sums[2] + warp_sums[3]);
        g[bc] = tot * (1.0f / HW);
    }
}

// ---------------- Kernel 2: 1x1 conv (768x256 dot) + BN + tanh ----------------
// grid (6, 32): blockIdx.y = batch, blockIdx.x = 128-row group.
// Each wave owns 32 rows; lanes read cw[row,:] as coalesced float4, shfl-reduce.
__global__ __launch_bounds__(256) void filt_kernel(const float* __restrict__ g,
                                                   const float* __restrict__ cw,
                                                   const float* __restrict__ bn_w,
                                                   const float* __restrict__ bn_b,
                                                   const float* __restrict__ bn_m,
                                                   const float* __restrict__ bn_v,
                                                   float* __restrict__ f) {
    const int b = blockIdx.y;
    const int t = threadIdx.x;
    __shared__ float gs[NC];
    gs[t] = g[b * NC + t];
    __syncthreads();
    const int wave = t >> 6, lane = t & 63;
    const f32x4 gv = reinterpret_cast<const f32x4*>(gs)[lane];  // gs[lane*4 .. +3]
    const int row0 = blockIdx.x * 128 + wave * 32;
#pragma unroll 4
    for (int i = 0; i < 32; ++i) {
        const int j = row0 + i;
        const f32x4 wv = reinterpret_cast<const f32x4*>(cw + (size_t)j * NC)[lane];
        float s = fmaf(gv.x, wv.x, fmaf(gv.y, wv.y, fmaf(gv.z, wv.z, gv.w * wv.w)));
#pragma unroll
        for (int off = 32; off > 0; off >>= 1) s += __shfl_down(s, off, 64);
        if (lane == 0) {
            float yn = (s - bn_m[j]) * rsqrtf(bn_v[j] + BN_EPS) * bn_w[j] + bn_b[j];
            f[b * KC + j] = tanhf(yn);
        }
    }
}

// ---------------- Kernel 3: dynamic channel-local filter + affine ----------------
// Block owns (b, 64-channel group, 256-float4 hw chunk). Sliding 3-plane
// register window along c: each x element loaded ONCE. Nontemporal stores
// keep out's 134MB write stream from evicting the gap-warmed x in L3.
__global__ __launch_bounds__(256) void apply_kernel(const float* __restrict__ x,
                                                    const float* __restrict__ f,
                                                    const float* __restrict__ gamma,
                                                    const float* __restrict__ beta,
                                                    float* __restrict__ out) {
    const int bid = blockIdx.x;          // 512 blocks
    const int b   = bid >> 4;
    const int cg  = (bid >> 2) & 3;
    const int hwt = bid & 3;
    const int t = threadIdx.x;
    const int hw = hwt * 256 + t;        // float4 index within plane
    const int c0 = cg * 64;

    const f32x4* x4 = reinterpret_cast<const f32x4*>(x) + (size_t)b * NC * HW4 + hw;
    f32x4* o4 = reinterpret_cast<f32x4*>(out) + (size_t)b * NC * HW4 + hw;
    const float* fb = f + b * KC;

    f32x4 cur = x4[(size_t)c0 * HW4];
    f32x4 nxt = x4[(size_t)(c0 + 1) * HW4];
    f32x4 prv = (c0 == 0) ? nxt : x4[(size_t)(c0 - 1) * HW4];

#pragma unroll 4
    for (int ci = 0; ci < 64; ++ci) {
        const int c = c0 + ci;
        const int cn = (c + 2 < NC) ? (c + 2) : (NC - 1);
        f32x4 nn = x4[(size_t)cn * HW4];          // prefetch for next iter
        const float f0 = fb[c];
        const float f1 = fb[NC + c];
        const float f2 = fb[2 * NC + c];
        const float ga = gamma[c];
        const float be = beta[c];
        const f32x4 xm = (c == 0) ? nxt : prv;        // reflect left edge
        const f32x4 xq = (c == NC - 1) ? prv : nxt;   // reflect right edge
        f32x4 r;
        r.x = fmaf(fmaf(f0, xm.x, fmaf(f1, cur.x, f2 * xq.x)), ga, cur.x * be);
        r.y = fmaf(fmaf(f0, xm.y, fmaf(f1, cur.y, f2 * xq.y)), ga, cur.y * be);
        r.z = fmaf(fmaf(f0, xm.z, fmaf(f1, cur.z, f2 * xq.z)), ga, cur.z * be);
        r.w = fmaf(fmaf(f0, xm.w, fmaf(f1, cur.w, f2 * xq.w)), ga, cur.w * be);
        __builtin_nontemporal_store(r, &o4[(size_t)c * HW4]);
        prv = cur; cur = nxt; nxt = nn;
    }
}

extern "C" void kernel_launch(void* const* d_in, const int* in_sizes, int n_in,
                              void* d_out, int out_size, void* d_ws, size_t ws_size,
                              hipStream_t stream) {
    const float* x     = (const float*)d_in[0];
    const float* cw    = (const float*)d_in[1];
    const float* bn_w  = (const float*)d_in[2];
    const float* bn_b  = (const float*)d_in[3];
    const float* bn_m  = (const float*)d_in[4];
    const float* bn_v  = (const float*)d_in[5];
    const float* gamma = (const float*)d_in[6];
    const float* beta  = (const float*)d_in[7];
    float* out = (float*)d_out;

    float* g = (float*)d_ws;                    // NB*NC floats
    float* f = g + NB * NC;                     // NB*KC floats

    gap_kernel<<<NB * NC, 256, 0, stream>>>(x, g);
    filt_kernel<<<dim3(6, NB), 256, 0, stream>>>(g, cw, bn_w, bn_b, bn_m, bn_v, f);
    apply_kernel<<<512, 256, 0, stream>>>(x, f, gamma, beta, out);
}